// Round 1
// baseline (796.324 us; speedup 1.0000x reference)
//
#include <hip/hip_runtime.h>
#include <math.h>

#define BATCH 16
#define EMB   32
#define HW    262144          // 512*512
#define NL    3

#define BLOCKS_PER_IMG 128
#define PX_PER_BLOCK  (HW / BLOCKS_PER_IMG)   // 2048
#define TILE_PX       128
#define N_ITERS       (PX_PER_BLOCK / TILE_PX) // 16

// ---- workspace layout (floats) ----
#define WS_COUNTS 0                     // BATCH*4
#define WS_SE     64                    // BATCH*96  sum_emb[b][l][e]
#define WS_SH     (WS_SE + BATCH*96)    // BATCH*96  sum_hat[b][l][e]
#define WS_CE     (WS_SH + BATCH*96)    // 1
#define WS_FLOATS (WS_CE + 1)

// ============================================================================
// Kernel 1: one pass over embedding. Per (b,l,e) accumulate sum_emb, sum_hat,
// and per (b,l) counts. Thread = (eg, ps): 4 channels (eg*4..+3) x 4 pixels.
// ============================================================================
__global__ __launch_bounds__(256) void accum_kernel(
        const float* __restrict__ emb, const int* __restrict__ label,
        float* __restrict__ ws)
{
    const int tid = threadIdx.x;
    const int ps  = tid & 31;          // pixel-slot 0..31
    const int eg  = tid >> 5;          // channel group 0..7
    const int wv  = tid >> 6;          // wave 0..3
    const bool lowHalf = (tid & 63) < 32;
    const int b   = blockIdx.x / BLOCKS_PER_IMG;
    const int blk = blockIdx.x % BLOCKS_PER_IMG;

    const float* embB = emb + (size_t)b * EMB * HW;
    const int*   labB = label + (size_t)b * HW;
    const size_t pixBase = (size_t)blk * PX_PER_BLOCK;

    __shared__ float4 part[4][32];

    float accE[NL][4] = {};   // [label][k] for channels eg*4+k
    float accH[NL][4] = {};
    float cnt[NL] = {0.f, 0.f, 0.f};

    for (int it = 0; it < N_ITERS; ++it) {
        const size_t p = pixBase + (size_t)it * TILE_PX + (size_t)ps * 4;
        // 4 channels x 4 consecutive pixels, fully coalesced float4 loads
        const float4 v0 = *(const float4*)(embB + (size_t)(eg*4+0)*HW + p);
        const float4 v1 = *(const float4*)(embB + (size_t)(eg*4+1)*HW + p);
        const float4 v2 = *(const float4*)(embB + (size_t)(eg*4+2)*HW + p);
        const float4 v3 = *(const float4*)(embB + (size_t)(eg*4+2)*HW + p - 2*HW + 3*HW); // v3 placeholder fixed below
        const float4 v3r = *(const float4*)(embB + (size_t)(eg*4+3)*HW + p);
        const int4 lab  = *(const int4*)(labB + p);
        const float4 V3 = v3r; (void)v3;

        // partial sum-of-squares per pixel (over this thread's 4 channels)
        float4 s;
        s.x = v0.x*v0.x + v1.x*v1.x + v2.x*v2.x + V3.x*V3.x;
        s.y = v0.y*v0.y + v1.y*v1.y + v2.y*v2.y + V3.y*V3.y;
        s.z = v0.z*v0.z + v1.z*v1.z + v2.z*v2.z + V3.z*V3.z;
        s.w = v0.w*v0.w + v1.w*v1.w + v2.w*v2.w + V3.w*V3.w;
        // reduce over channel-group pair within wave (eg ^ 1)
        s.x += __shfl_xor(s.x, 32);
        s.y += __shfl_xor(s.y, 32);
        s.z += __shfl_xor(s.z, 32);
        s.w += __shfl_xor(s.w, 32);
        if (lowHalf) part[wv][ps] = s;
        __syncthreads();
        const float4 t0 = part[0][ps], t1 = part[1][ps],
                     t2 = part[2][ps], t3 = part[3][ps];
        float invn[4];
        invn[0] = 1.0f / fmaxf(sqrtf(t0.x + t1.x + t2.x + t3.x), 1e-8f);
        invn[1] = 1.0f / fmaxf(sqrtf(t0.y + t1.y + t2.y + t3.y), 1e-8f);
        invn[2] = 1.0f / fmaxf(sqrtf(t0.z + t1.z + t2.z + t3.z), 1e-8f);
        invn[3] = 1.0f / fmaxf(sqrtf(t0.w + t1.w + t2.w + t3.w), 1e-8f);
        __syncthreads();

        const float chv[4][4] = {   // [pixel j][channel k]
            {v0.x, v1.x, v2.x, V3.x},
            {v0.y, v1.y, v2.y, V3.y},
            {v0.z, v1.z, v2.z, V3.z},
            {v0.w, v1.w, v2.w, V3.w}};
        const int labs[4] = {lab.x, lab.y, lab.z, lab.w};

        #pragma unroll
        for (int j = 0; j < 4; ++j) {
            const float m0 = (labs[j] == 0) ? 1.f : 0.f;
            const float m1 = (labs[j] == 1) ? 1.f : 0.f;
            const float m2 = (labs[j] == 2) ? 1.f : 0.f;
            const float iv = invn[j];
            if (eg == 0) { cnt[0] += m0; cnt[1] += m1; cnt[2] += m2; }
            #pragma unroll
            for (int k = 0; k < 4; ++k) {
                const float v  = chv[j][k];
                const float vh = v * iv;
                accE[0][k] = fmaf(m0, v,  accE[0][k]);
                accE[1][k] = fmaf(m1, v,  accE[1][k]);
                accE[2][k] = fmaf(m2, v,  accE[2][k]);
                accH[0][k] = fmaf(m0, vh, accH[0][k]);
                accH[1][k] = fmaf(m1, vh, accH[1][k]);
                accH[2][k] = fmaf(m2, vh, accH[2][k]);
            }
        }
    }

    // reduce over the 32 pixel-slots (same eg = same 32-lane half-wave)
    #pragma unroll
    for (int o = 16; o >= 1; o >>= 1) {
        #pragma unroll
        for (int l = 0; l < NL; ++l) {
            #pragma unroll
            for (int k = 0; k < 4; ++k) {
                accE[l][k] += __shfl_xor(accE[l][k], o);
                accH[l][k] += __shfl_xor(accH[l][k], o);
            }
            cnt[l] += __shfl_xor(cnt[l], o);
        }
    }
    if (ps == 0) {
        float* se = ws + WS_SE + b * 96;
        float* sh = ws + WS_SH + b * 96;
        #pragma unroll
        for (int l = 0; l < NL; ++l) {
            #pragma unroll
            for (int k = 0; k < 4; ++k) {
                atomicAdd(&se[l*32 + eg*4 + k], accE[l][k]);
                atomicAdd(&sh[l*32 + eg*4 + k], accH[l][k]);
            }
        }
        if (eg == 0) {
            atomicAdd(&ws[WS_COUNTS + b*4 + 0], cnt[0]);
            atomicAdd(&ws[WS_COUNTS + b*4 + 1], cnt[1]);
            atomicAdd(&ws[WS_COUNTS + b*4 + 2], cnt[2]);
        }
    }
}

// ============================================================================
// Kernel 2: cross-entropy over prediction logits (3 classes, axis 0).
// Accumulates sum(lse - z_label)/HW into ws[WS_CE].
// ============================================================================
__device__ __forceinline__ float ce1(float a, float b, float c, int l) {
    const float m = fmaxf(fmaxf(a, b), c);
    const float s = __expf(a - m) + __expf(b - m) + __expf(c - m);
    const float zl = (l == 0) ? a : ((l == 1) ? b : c);
    return m + __logf(s) - zl;
}

__global__ __launch_bounds__(256) void ce_kernel(
        const float* __restrict__ pred, const int* __restrict__ label,
        float* __restrict__ ws)
{
    const long P4 = HW / 4;
    const long nq = (long)BATCH * P4;
    float local = 0.f;
    for (long q = (long)blockIdx.x * blockDim.x + threadIdx.x; q < nq;
         q += (long)gridDim.x * blockDim.x) {
        const int b  = (int)(q / P4);
        const long p = (q % P4) * 4;
        const float* pb = pred + (size_t)b * 3 * HW;
        const float4 z0 = *(const float4*)(pb + p);
        const float4 z1 = *(const float4*)(pb + HW + p);
        const float4 z2 = *(const float4*)(pb + 2 * HW + p);
        const int4 lab  = *(const int4*)(label + (size_t)b * HW + p);
        local += ce1(z0.x, z1.x, z2.x, lab.x);
        local += ce1(z0.y, z1.y, z2.y, lab.y);
        local += ce1(z0.z, z1.z, z2.z, lab.z);
        local += ce1(z0.w, z1.w, z2.w, lab.w);
    }
    #pragma unroll
    for (int o = 32; o >= 1; o >>= 1) local += __shfl_xor(local, o);
    __shared__ float wsum[4];
    if ((threadIdx.x & 63) == 0) wsum[threadIdx.x >> 6] = local;
    __syncthreads();
    if (threadIdx.x == 0) {
        const float t = wsum[0] + wsum[1] + wsum[2] + wsum[3];
        atomicAdd(&ws[WS_CE], t * (1.0f / (float)HW));
    }
}

// ============================================================================
// Kernel 3: finalize. Block 512 = 16 images x 32 channels.
// ============================================================================
__global__ __launch_bounds__(512) void final_kernel(
        const int* __restrict__ nbr, const float* __restrict__ ws,
        float* __restrict__ out)
{
    const int tid = threadIdx.x;
    const int b = tid >> 5;
    const int e = tid & 31;
    __shared__ float total;
    if (tid == 0) total = 0.f;
    __syncthreads();

    const float* se = ws + WS_SE + b * 96;
    const float* sh = ws + WS_SH + b * 96;
    const float c0 = ws[WS_COUNTS + b*4 + 0];
    const float c1 = ws[WS_COUNTS + b*4 + 1];
    const float c2 = ws[WS_COUNTS + b*4 + 2];

    float mean0 = se[0*32 + e] / c0;
    float mean1 = se[1*32 + e] / c1;
    float mean2 = se[2*32 + e] / c2;

    float n0 = mean0*mean0, n1 = mean1*mean1, n2 = mean2*mean2;
    #pragma unroll
    for (int o = 16; o >= 1; o >>= 1) {
        n0 += __shfl_xor(n0, o);
        n1 += __shfl_xor(n1, o);
        n2 += __shfl_xor(n2, o);
    }
    const float nm0 = mean0 / fmaxf(sqrtf(n0), 1e-12f);
    const float nm1 = mean1 / fmaxf(sqrtf(n1), 1e-12f);
    const float nm2 = mean2 / fmaxf(sqrtf(n2), 1e-12f);

    float d1  = nm1 * sh[1*32 + e];
    float d2  = nm2 * sh[2*32 + e];
    float s10 = nm1 * nm0, s11 = nm1 * nm1, s12 = nm1 * nm2;
    float s20 = nm2 * nm0, s21 = nm2 * nm1, s22 = nm2 * nm2;
    #pragma unroll
    for (int o = 16; o >= 1; o >>= 1) {
        d1  += __shfl_xor(d1, o);  d2  += __shfl_xor(d2, o);
        s10 += __shfl_xor(s10, o); s11 += __shfl_xor(s11, o); s12 += __shfl_xor(s12, o);
        s20 += __shfl_xor(s20, o); s21 += __shfl_xor(s21, o); s22 += __shfl_xor(s22, o);
    }

    if (e == 0) {
        float S[3][3];
        S[1][0] = s10; S[1][1] = s11; S[1][2] = s12;
        S[2][0] = s20; S[2][1] = s21; S[2][2] = s22;
        S[0][0] = S[0][1] = S[0][2] = 0.f;
        float mask[3][3] = {{0.f,0.f,0.f},{0.f,0.f,0.f},{0.f,0.f,0.f}};
        for (int row = 1; row < 3; ++row) {
            int prod = 1;
            for (int j = 0; j < 3; ++j) {
                const int v = nbr[b*9 + row*3 + j];
                if (v == 0) prod = 0;           // cumprod includes current elem
                if (prod) mask[row][v] = 1.f;   // scatter-max
            }
        }
        float num = 0.f, den = 0.f;
        for (int row = 1; row < 3; ++row)
            for (int col = 0; col < 3; ++col) {
                num += S[row][col] * mask[row][col];
                den += mask[row][col];
            }
        const float inter = num / den;
        const float ip1 = 1.f - d1 / c1;
        const float ip2 = 1.f - d2 / c2;
        const float loss = 0.5f * (ip1 + ip2) + inter;
        atomicAdd(&total, loss);
    }
    __syncthreads();
    if (tid == 0) out[0] = total + ws[WS_CE];
}

// ============================================================================
extern "C" void kernel_launch(void* const* d_in, const int* in_sizes, int n_in,
                              void* d_out, int out_size, void* d_ws, size_t ws_size,
                              hipStream_t stream) {
    const float* emb   = (const float*)d_in[0];
    const float* pred  = (const float*)d_in[1];
    const int*   label = (const int*)d_in[2];
    const int*   nbr   = (const int*)d_in[3];
    float* ws  = (float*)d_ws;
    float* out = (float*)d_out;

    hipMemsetAsync(d_ws, 0, WS_FLOATS * sizeof(float), stream);
    accum_kernel<<<BATCH * BLOCKS_PER_IMG, 256, 0, stream>>>(emb, label, ws);
    ce_kernel<<<2048, 256, 0, stream>>>(pred, label, ws);
    final_kernel<<<1, 512, 0, stream>>>(nbr, ws, out);
}

// Round 2
// 768.707 us; speedup vs baseline: 1.0359x; 1.0359x over previous
//
#include <hip/hip_runtime.h>
#include <math.h>

#define BATCH 16
#define EMB   32
#define HW    262144          // 512*512
#define NL    3

#define BLOCKS_PER_IMG 128
#define PX_PER_BLOCK  (HW / BLOCKS_PER_IMG)   // 2048
#define TILE_PX       128
#define N_ITERS       (PX_PER_BLOCK / TILE_PX) // 16

// ---- workspace layout (floats) ----
#define WS_COUNTS 0                     // BATCH*4
#define WS_SE     64                    // BATCH*96  sum_emb[b][l][e]
#define WS_SH     (WS_SE + BATCH*96)    // BATCH*96  sum_hat[b][l][e]
#define WS_CE     (WS_SH + BATCH*96)    // 1
#define WS_FLOATS (WS_CE + 1)

__device__ __forceinline__ float ce1(float a, float b, float c, int l) {
    const float m = fmaxf(fmaxf(a, b), c);
    const float s = __expf(a - m) + __expf(b - m) + __expf(c - m);
    const float zl = (l == 0) ? a : ((l == 1) ? b : c);
    return m + __logf(s) - zl;
}

// ============================================================================
// Fused kernel: ONE pass over embedding + prediction + labels.
//   - per (b,l,e): sum_emb, sum_hat (emb/||emb||); per (b,l): counts
//   - CE: iteration it's 128 pixels handled by channel-group eg==(it&7)
// Thread = (eg, ps): channels eg*4..+3  x  pixels ps*4..+3 of each tile.
// One barrier/iter (double-buffered LDS norm exchange) + prefetch of it+1.
// ============================================================================
__global__ __launch_bounds__(256) void fused_kernel(
        const float* __restrict__ emb, const float* __restrict__ pred,
        const int* __restrict__ label, float* __restrict__ ws)
{
    const int tid = threadIdx.x;
    const int ps  = tid & 31;          // pixel-slot 0..31
    const int eg  = tid >> 5;          // channel group 0..7
    const int wv  = tid >> 6;          // wave 0..3
    const bool lowHalf = (tid & 63) < 32;
    const int b   = blockIdx.x / BLOCKS_PER_IMG;
    const int blk = blockIdx.x % BLOCKS_PER_IMG;

    const float* embB  = emb  + (size_t)b * EMB * HW;
    const float* predB = pred + (size_t)b * 3 * HW;
    const int*   labB  = label + (size_t)b * HW;
    const size_t pixBase = (size_t)blk * PX_PER_BLOCK;

    const float* ch0 = embB + (size_t)(eg*4+0)*HW;
    const float* ch1 = embB + (size_t)(eg*4+1)*HW;
    const float* ch2 = embB + (size_t)(eg*4+2)*HW;
    const float* ch3 = embB + (size_t)(eg*4+3)*HW;

    __shared__ float4 part[2][4][32];   // [buf][wave][pixel-slot]

    float accE[NL][4] = {};   // [label][k] for channels eg*4+k
    float accH[NL][4] = {};
    float cnt[NL] = {0.f, 0.f, 0.f};
    float ce = 0.f;

    // prologue: load tile 0
    size_t p = pixBase + (size_t)ps * 4;
    float4 v0 = *(const float4*)(ch0 + p);
    float4 v1 = *(const float4*)(ch1 + p);
    float4 v2 = *(const float4*)(ch2 + p);
    float4 v3 = *(const float4*)(ch3 + p);
    int4  lab = *(const int4*)(labB + p);

    for (int it = 0; it < N_ITERS; ++it) {
        // ---- prefetch next tile (wraps to tile 0 on last iter: L2-hot, keeps
        //      the loop branch-free and regs always initialized) ----
        const size_t pn = (it + 1 < N_ITERS) ? (p + TILE_PX)
                                             : (pixBase + (size_t)ps * 4);
        const float4 n0 = *(const float4*)(ch0 + pn);
        const float4 n1 = *(const float4*)(ch1 + pn);
        const float4 n2 = *(const float4*)(ch2 + pn);
        const float4 n3 = *(const float4*)(ch3 + pn);
        const int4 nlab = *(const int4*)(labB + pn);

        // ---- CE loads for CURRENT tile (one channel-group owns this iter) ----
        const bool doCE = (eg == (it & 7));
        float4 z0, z1, z2;
        if (doCE) {
            z0 = *(const float4*)(predB + p);
            z1 = *(const float4*)(predB + HW + p);
            z2 = *(const float4*)(predB + 2*HW + p);
        }

        // ---- per-pixel sum of squares over this thread's 4 channels ----
        float4 s;
        s.x = v0.x*v0.x + v1.x*v1.x + v2.x*v2.x + v3.x*v3.x;
        s.y = v0.y*v0.y + v1.y*v1.y + v2.y*v2.y + v3.y*v3.y;
        s.z = v0.z*v0.z + v1.z*v1.z + v2.z*v2.z + v3.z*v3.z;
        s.w = v0.w*v0.w + v1.w*v1.w + v2.w*v2.w + v3.w*v3.w;
        // fold the partner channel-group in the same wave (lane ^ 32)
        s.x += __shfl_xor(s.x, 32);
        s.y += __shfl_xor(s.y, 32);
        s.z += __shfl_xor(s.z, 32);
        s.w += __shfl_xor(s.w, 32);
        if (lowHalf) part[it & 1][wv][ps] = s;
        __syncthreads();
        const float4 t0 = part[it & 1][0][ps];
        const float4 t1 = part[it & 1][1][ps];
        const float4 t2 = part[it & 1][2][ps];
        const float4 t3 = part[it & 1][3][ps];
        float invn[4];
        invn[0] = 1.0f / fmaxf(sqrtf(t0.x + t1.x + t2.x + t3.x), 1e-8f);
        invn[1] = 1.0f / fmaxf(sqrtf(t0.y + t1.y + t2.y + t3.y), 1e-8f);
        invn[2] = 1.0f / fmaxf(sqrtf(t0.z + t1.z + t2.z + t3.z), 1e-8f);
        invn[3] = 1.0f / fmaxf(sqrtf(t0.w + t1.w + t2.w + t3.w), 1e-8f);
        // NOTE: no second barrier — next iter writes the OTHER buffer, and the
        // it+2 overwrite of this buffer is fenced by iter it+1's barrier.

        const float chv[4][4] = {   // [pixel j][channel k]
            {v0.x, v1.x, v2.x, v3.x},
            {v0.y, v1.y, v2.y, v3.y},
            {v0.z, v1.z, v2.z, v3.z},
            {v0.w, v1.w, v2.w, v3.w}};
        const int labs[4] = {lab.x, lab.y, lab.z, lab.w};

        #pragma unroll
        for (int j = 0; j < 4; ++j) {
            const float m0 = (labs[j] == 0) ? 1.f : 0.f;
            const float m1 = (labs[j] == 1) ? 1.f : 0.f;
            const float m2 = (labs[j] == 2) ? 1.f : 0.f;
            const float iv = invn[j];
            if (eg == 0) { cnt[0] += m0; cnt[1] += m1; cnt[2] += m2; }
            #pragma unroll
            for (int k = 0; k < 4; ++k) {
                const float v  = chv[j][k];
                const float vh = v * iv;
                accE[0][k] = fmaf(m0, v,  accE[0][k]);
                accE[1][k] = fmaf(m1, v,  accE[1][k]);
                accE[2][k] = fmaf(m2, v,  accE[2][k]);
                accH[0][k] = fmaf(m0, vh, accH[0][k]);
                accH[1][k] = fmaf(m1, vh, accH[1][k]);
                accH[2][k] = fmaf(m2, vh, accH[2][k]);
            }
        }

        if (doCE) {
            ce += ce1(z0.x, z1.x, z2.x, labs[0]);
            ce += ce1(z0.y, z1.y, z2.y, labs[1]);
            ce += ce1(z0.z, z1.z, z2.z, labs[2]);
            ce += ce1(z0.w, z1.w, z2.w, labs[3]);
        }

        v0 = n0; v1 = n1; v2 = n2; v3 = n3; lab = nlab; p = pn;
    }

    // ---- reduce over the 32 pixel-slots (stays within each eg's half-wave) --
    #pragma unroll
    for (int o = 16; o >= 1; o >>= 1) {
        #pragma unroll
        for (int l = 0; l < NL; ++l) {
            #pragma unroll
            for (int k = 0; k < 4; ++k) {
                accE[l][k] += __shfl_xor(accE[l][k], o);
                accH[l][k] += __shfl_xor(accH[l][k], o);
            }
            cnt[l] += __shfl_xor(cnt[l], o);
        }
        ce += __shfl_xor(ce, o);
    }
    if (ps == 0) {
        float* se = ws + WS_SE + b * 96;
        float* sh = ws + WS_SH + b * 96;
        #pragma unroll
        for (int l = 0; l < NL; ++l) {
            #pragma unroll
            for (int k = 0; k < 4; ++k) {
                atomicAdd(&se[l*32 + eg*4 + k], accE[l][k]);
                atomicAdd(&sh[l*32 + eg*4 + k], accH[l][k]);
            }
        }
        atomicAdd(&ws[WS_CE], ce * (1.0f / (float)HW));
        if (eg == 0) {
            atomicAdd(&ws[WS_COUNTS + b*4 + 0], cnt[0]);
            atomicAdd(&ws[WS_COUNTS + b*4 + 1], cnt[1]);
            atomicAdd(&ws[WS_COUNTS + b*4 + 2], cnt[2]);
        }
    }
}

// ============================================================================
// Finalize. Block 512 = 16 images x 32 channels.
// ============================================================================
__global__ __launch_bounds__(512) void final_kernel(
        const int* __restrict__ nbr, const float* __restrict__ ws,
        float* __restrict__ out)
{
    const int tid = threadIdx.x;
    const int b = tid >> 5;
    const int e = tid & 31;
    __shared__ float total;
    if (tid == 0) total = 0.f;
    __syncthreads();

    const float* se = ws + WS_SE + b * 96;
    const float* sh = ws + WS_SH + b * 96;
    const float c0 = ws[WS_COUNTS + b*4 + 0];
    const float c1 = ws[WS_COUNTS + b*4 + 1];
    const float c2 = ws[WS_COUNTS + b*4 + 2];

    float mean0 = se[0*32 + e] / c0;
    float mean1 = se[1*32 + e] / c1;
    float mean2 = se[2*32 + e] / c2;

    float n0 = mean0*mean0, n1 = mean1*mean1, n2 = mean2*mean2;
    #pragma unroll
    for (int o = 16; o >= 1; o >>= 1) {
        n0 += __shfl_xor(n0, o);
        n1 += __shfl_xor(n1, o);
        n2 += __shfl_xor(n2, o);
    }
    const float nm0 = mean0 / fmaxf(sqrtf(n0), 1e-12f);
    const float nm1 = mean1 / fmaxf(sqrtf(n1), 1e-12f);
    const float nm2 = mean2 / fmaxf(sqrtf(n2), 1e-12f);

    float d1  = nm1 * sh[1*32 + e];
    float d2  = nm2 * sh[2*32 + e];
    float s10 = nm1 * nm0, s11 = nm1 * nm1, s12 = nm1 * nm2;
    float s20 = nm2 * nm0, s21 = nm2 * nm1, s22 = nm2 * nm2;
    #pragma unroll
    for (int o = 16; o >= 1; o >>= 1) {
        d1  += __shfl_xor(d1, o);  d2  += __shfl_xor(d2, o);
        s10 += __shfl_xor(s10, o); s11 += __shfl_xor(s11, o); s12 += __shfl_xor(s12, o);
        s20 += __shfl_xor(s20, o); s21 += __shfl_xor(s21, o); s22 += __shfl_xor(s22, o);
    }

    if (e == 0) {
        float S[3][3];
        S[1][0] = s10; S[1][1] = s11; S[1][2] = s12;
        S[2][0] = s20; S[2][1] = s21; S[2][2] = s22;
        S[0][0] = S[0][1] = S[0][2] = 0.f;
        float mask[3][3] = {{0.f,0.f,0.f},{0.f,0.f,0.f},{0.f,0.f,0.f}};
        for (int row = 1; row < 3; ++row) {
            int prod = 1;
            for (int j = 0; j < 3; ++j) {
                const int v = nbr[b*9 + row*3 + j];
                if (v == 0) prod = 0;           // cumprod includes current elem
                if (prod) mask[row][v] = 1.f;   // scatter-max
            }
        }
        float num = 0.f, den = 0.f;
        for (int row = 1; row < 3; ++row)
            for (int col = 0; col < 3; ++col) {
                num += S[row][col] * mask[row][col];
                den += mask[row][col];
            }
        const float inter = num / den;
        const float ip1 = 1.f - d1 / c1;
        const float ip2 = 1.f - d2 / c2;
        const float loss = 0.5f * (ip1 + ip2) + inter;
        atomicAdd(&total, loss);
    }
    __syncthreads();
    if (tid == 0) out[0] = total + ws[WS_CE];
}

// ============================================================================
extern "C" void kernel_launch(void* const* d_in, const int* in_sizes, int n_in,
                              void* d_out, int out_size, void* d_ws, size_t ws_size,
                              hipStream_t stream) {
    const float* emb   = (const float*)d_in[0];
    const float* pred  = (const float*)d_in[1];
    const int*   label = (const int*)d_in[2];
    const int*   nbr   = (const int*)d_in[3];
    float* ws  = (float*)d_ws;
    float* out = (float*)d_out;

    hipMemsetAsync(d_ws, 0, WS_FLOATS * sizeof(float), stream);
    fused_kernel<<<BATCH * BLOCKS_PER_IMG, 256, 0, stream>>>(emb, pred, label, ws);
    final_kernel<<<1, 512, 0, stream>>>(nbr, ws, out);
}